// Round 1
// baseline (2299.650 us; speedup 1.0000x reference)
//
#include <hip/hip_runtime.h>
#include <cstdint>
#include <cstddef>

// NaryTreeLSTM: complete binary tree, DEPTH=16, N_NODES=65535, D_IN=H=256, K=2.
// Bottom-up level sweep. Per level: GEMM (z=[x|h_l|h_r] @ Wbig^T + bias) then
// pointwise gates. Children of level-l node m are level-(l+1) local 2m, 2m+1,
// so child h/c buffers viewed [n, 512] give the concat for free.
//
// Wbig [1280 x 768] packed rows:
//   j in [0,256):    i-gate dim d=j      : [W_i[d,:] | U_i0[d,:] | U_i1[d,:]]
//   j in [256,512):  o-gate dim d=j-256  : [W_o | U_o0 | U_o1]
//   j in [512,768):  u-gate dim d=j-512  : [W_u | U_u0 | U_u1]
//   j in [768,1024): f_left  d=j-768     : [W_f | U_f0 | 0]
//   j in [1024,1280):f_right d=j-1024    : [W_f | 0 | U_f1]

#define HDIM 256

__device__ __forceinline__ float sigf(float x) { return 1.0f / (1.0f + __expf(-x)); }

__global__ void pack_weights(const float* __restrict__ Wi, const float* __restrict__ bi, const float* __restrict__ Ui,
                             const float* __restrict__ Wo, const float* __restrict__ bo, const float* __restrict__ Uo,
                             const float* __restrict__ Wu, const float* __restrict__ bu, const float* __restrict__ Uu,
                             const float* __restrict__ Wf, const float* __restrict__ bf, const float* __restrict__ Uf,
                             float* __restrict__ Wbig, float* __restrict__ biasbig)
{
    int j = blockIdx.x;    // 0..1279 output row
    int k = threadIdx.x;   // 0..255 col within 256-block
    const float *W, *b, *U0, *U1;
    int d;
    if (j < 256)        { W = Wi; b = bi; U0 = Ui;          U1 = Ui + 65536; d = j; }
    else if (j < 512)   { W = Wo; b = bo; U0 = Uo;          U1 = Uo + 65536; d = j - 256; }
    else if (j < 768)   { W = Wu; b = bu; U0 = Uu;          U1 = Uu + 65536; d = j - 512; }
    else if (j < 1024)  { W = Wf; b = bf; U0 = Uf;          U1 = nullptr;    d = j - 768; }
    else                { W = Wf; b = bf; U0 = nullptr;     U1 = Uf + 65536; d = j - 1024; }
    float* row = Wbig + (size_t)j * 768;
    row[k]         = W[d * 256 + k];
    row[256 + k]   = U0 ? U0[d * 256 + k] : 0.0f;
    row[512 + k]   = U1 ? U1[d * 256 + k] : 0.0f;
    if (k == 0) biasbig[j] = b[d];
}

// C[M x Nld] = A_virtual[M x Kd] * Wbig[rows x 768]^T + bias
// A_virtual(m,k) = (k < 256) ? embX[m*256 + k] : hprev[m*512 + (k-256)]
// BM=BN=64, BK=16, 256 threads, 4x4 micro-tile per thread.
__global__ __launch_bounds__(256) void level_gemm(
    const float* __restrict__ embX,
    const float* __restrict__ hprev,
    const float* __restrict__ Wbig,
    const float* __restrict__ biasbig,
    float* __restrict__ R,
    int M, int Nld, int Kd)
{
    __shared__ float As[16][65];
    __shared__ float Bs[16][65];
    const int bn0 = blockIdx.x * 64;
    const int bm0 = blockIdx.y * 64;
    const int tid = threadIdx.x;
    const int tx = tid & 15;   // n direction
    const int ty = tid >> 4;   // m direction
    float acc[4][4] = {};

    for (int k0 = 0; k0 < Kd; k0 += 16) {
        // Load A tile: 64 rows x 16 cols; thread t: m = t>>2, k = (t&3)*4 (float4)
        {
            int m = tid >> 2;
            int k = (tid & 3) * 4;
            int gm = bm0 + m;
            float4 v = {0.f, 0.f, 0.f, 0.f};
            if (gm < M) {
                int gk = k0 + k;
                const float* src = (gk < 256) ? &embX[(size_t)gm * 256 + gk]
                                              : &hprev[(size_t)gm * 512 + (gk - 256)];
                v = *(const float4*)src;
            }
            As[k + 0][m] = v.x; As[k + 1][m] = v.y; As[k + 2][m] = v.z; As[k + 3][m] = v.w;
        }
        // Load B tile: 64 rows x 16 cols of Wbig (row stride 768)
        {
            int n = tid >> 2;
            int k = (tid & 3) * 4;
            float4 v = *(const float4*)&Wbig[(size_t)(bn0 + n) * 768 + k0 + k];
            Bs[k + 0][n] = v.x; Bs[k + 1][n] = v.y; Bs[k + 2][n] = v.z; Bs[k + 3][n] = v.w;
        }
        __syncthreads();
        #pragma unroll
        for (int kk = 0; kk < 16; ++kk) {
            float a[4], b[4];
            #pragma unroll
            for (int i = 0; i < 4; ++i) a[i] = As[kk][ty * 4 + i];
            #pragma unroll
            for (int j = 0; j < 4; ++j) b[j] = Bs[kk][tx * 4 + j];
            #pragma unroll
            for (int i = 0; i < 4; ++i)
                #pragma unroll
                for (int j = 0; j < 4; ++j)
                    acc[i][j] += a[i] * b[j];
        }
        __syncthreads();
    }

    #pragma unroll
    for (int i = 0; i < 4; ++i) {
        int gm = bm0 + ty * 4 + i;
        if (gm >= M) continue;
        #pragma unroll
        for (int j = 0; j < 4; ++j) {
            int gn = bn0 + tx * 4 + j;
            R[(size_t)gm * Nld + gn] = acc[i][j] + biasbig[gn];
        }
    }
}

__global__ void pointwise_internal(const float* __restrict__ R,      // [n x 1280]
                                   const float* __restrict__ cprev,  // [2n x 256]
                                   float* __restrict__ hout,         // [n x 256]
                                   float* __restrict__ cout,         // [n x 256]
                                   int n)
{
    int idx = blockIdx.x * 256 + threadIdx.x;
    if (idx >= n * 256) return;
    int m = idx >> 8, d = idx & 255;
    const float* r = R + (size_t)m * 1280;
    float i  = sigf(r[d]);
    float o  = sigf(r[256 + d]);
    float u  = tanhf(r[512 + d]);
    float fl = sigf(r[768 + d]);
    float fr = sigf(r[1024 + d]);
    float cl = cprev[(size_t)m * 512 + d];
    float cr = cprev[(size_t)m * 512 + 256 + d];
    float c = i * u + fl * cl + fr * cr;
    cout[idx] = c;
    hout[idx] = o * tanhf(c);
}

__global__ void pointwise_leaf(const float* __restrict__ R,   // [n x 768]
                               float* __restrict__ hout,
                               float* __restrict__ cout,
                               int n)
{
    int idx = blockIdx.x * 256 + threadIdx.x;
    if (idx >= n * 256) return;
    int m = idx >> 8, d = idx & 255;
    const float* r = R + (size_t)m * 768;
    float i = sigf(r[d]);
    float o = sigf(r[256 + d]);
    float u = tanhf(r[512 + d]);
    float c = i * u;
    cout[idx] = c;
    hout[idx] = o * tanhf(c);
}

__global__ void write_out(const float* __restrict__ h, const float* __restrict__ c,
                          float* __restrict__ out)
{
    int t = threadIdx.x; // 256
    out[t] = h[t];
    out[256 + t] = c[t];
}

extern "C" void kernel_launch(void* const* d_in, const int* in_sizes, int n_in,
                              void* d_out, int out_size, void* d_ws, size_t ws_size,
                              hipStream_t stream)
{
    const float* emb = (const float*)d_in[0];
    const float* Wi  = (const float*)d_in[1];
    const float* bi  = (const float*)d_in[2];
    const float* Ui  = (const float*)d_in[3];
    const float* Wo  = (const float*)d_in[4];
    const float* bo  = (const float*)d_in[5];
    const float* Uo  = (const float*)d_in[6];
    const float* Wu  = (const float*)d_in[7];
    const float* bu  = (const float*)d_in[8];
    const float* Uu  = (const float*)d_in[9];
    const float* Wf  = (const float*)d_in[10];
    const float* bf  = (const float*)d_in[11];
    const float* Uf  = (const float*)d_in[12];

    float* ws      = (float*)d_ws;
    float* Wbig    = ws;                               // 1280*768      = 983040
    float* biasbig = Wbig + 1280 * 768;                // 1280
    float* hbuf    = biasbig + 1280;                   // 65535*256     = 16776960
    float* cbuf    = hbuf + 65535 * 256;               // 65535*256
    float* Rbuf    = cbuf + 65535 * 256;               // 32768*768     = 25165824 (max)

    pack_weights<<<1280, 256, 0, stream>>>(Wi, bi, Ui, Wo, bo, Uo, Wu, bu, Uu, Wf, bf, Uf,
                                           Wbig, biasbig);

    // Leaves: level 15, n = 32768, start = 32767. K=256 (x only), N=768 (i,o,u).
    {
        const int n = 32768, start = n - 1;
        level_gemm<<<dim3(768 / 64, n / 64), 256, 0, stream>>>(
            emb + (size_t)start * 256, nullptr, Wbig, biasbig, Rbuf, n, 768, 256);
        pointwise_leaf<<<n, 256, 0, stream>>>(
            Rbuf, hbuf + (size_t)start * 256, cbuf + (size_t)start * 256, n);
    }

    // Internal levels, bottom-up.
    for (int l = 14; l >= 0; --l) {
        const int n = 1 << l;
        const int start = n - 1;
        const int startc = 2 * n - 1;
        level_gemm<<<dim3(1280 / 64, (n + 63) / 64), 256, 0, stream>>>(
            emb + (size_t)start * 256, hbuf + (size_t)startc * 256,
            Wbig, biasbig, Rbuf, n, 1280, 768);
        pointwise_internal<<<n, 256, 0, stream>>>(
            Rbuf, cbuf + (size_t)startc * 256,
            hbuf + (size_t)start * 256, cbuf + (size_t)start * 256, n);
    }

    // Root = level 0 node 0 at offset 0: out = [h_root | c_root]
    write_out<<<1, 256, 0, stream>>>(hbuf, cbuf, (float*)d_out);
}

// Round 2
// 641.922 us; speedup vs baseline: 3.5824x; 3.5824x over previous
//
#include <hip/hip_runtime.h>
#include <hip/hip_bf16.h>
#include <cstdint>
#include <cstddef>

// NaryTreeLSTM bottom-up level sweep, bf16 MFMA GEMM per level.
// Wbig [1280 x 768] bf16, rows: [0,256)=i [256,512)=o [512,768)=u
// [768,1024)=f_left=[W_f|U_f0|0] [1024,1280)=f_right=[W_f|0|U_f1].
// A_virtual[m] = [x_m (256) | h_l (256) | h_r (256)], h stored bf16, c fp32.

typedef __attribute__((ext_vector_type(8))) __bf16 bf16x8;
typedef __attribute__((ext_vector_type(4))) float floatx4;

__device__ __forceinline__ float sigf(float x) { return 1.0f / (1.0f + __expf(-x)); }

__device__ __forceinline__ void load_lds16(const void* g, void* l) {
    __builtin_amdgcn_global_load_lds(
        (const __attribute__((address_space(1))) unsigned int*)g,
        (__attribute__((address_space(3))) unsigned int*)l, 16, 0, 0);
}

__global__ void pack_weights(const float* __restrict__ Wi, const float* __restrict__ bi, const float* __restrict__ Ui,
                             const float* __restrict__ Wo, const float* __restrict__ bo, const float* __restrict__ Uo,
                             const float* __restrict__ Wu, const float* __restrict__ bu, const float* __restrict__ Uu,
                             const float* __restrict__ Wf, const float* __restrict__ bf, const float* __restrict__ Uf,
                             __hip_bfloat16* __restrict__ Wbig, float* __restrict__ biasbig)
{
    int j = blockIdx.x;    // 0..1279 output row
    int k = threadIdx.x;   // 0..255
    const float *W, *b, *U0, *U1;
    int d;
    if (j < 256)        { W = Wi; b = bi; U0 = Ui;       U1 = Ui + 65536; d = j; }
    else if (j < 512)   { W = Wo; b = bo; U0 = Uo;       U1 = Uo + 65536; d = j - 256; }
    else if (j < 768)   { W = Wu; b = bu; U0 = Uu;       U1 = Uu + 65536; d = j - 512; }
    else if (j < 1024)  { W = Wf; b = bf; U0 = Uf;       U1 = nullptr;    d = j - 768; }
    else                { W = Wf; b = bf; U0 = nullptr;  U1 = Uf + 65536; d = j - 1024; }
    __hip_bfloat16* row = Wbig + (size_t)j * 768;
    row[k]       = __float2bfloat16(W[d * 256 + k]);
    row[256 + k] = __float2bfloat16(U0 ? U0[d * 256 + k] : 0.0f);
    row[512 + k] = __float2bfloat16(U1 ? U1[d * 256 + k] : 0.0f);
    if (k == 0) biasbig[j] = b[d];
}

__global__ void convert_f32_bf16(const float* __restrict__ in, __hip_bfloat16* __restrict__ out, int n4)
{
    int i = blockIdx.x * 256 + threadIdx.x;
    if (i >= n4) return;
    float4 v = ((const float4*)in)[i];
    __hip_bfloat16 tmp[4];
    tmp[0] = __float2bfloat16(v.x);
    tmp[1] = __float2bfloat16(v.y);
    tmp[2] = __float2bfloat16(v.z);
    tmp[3] = __float2bfloat16(v.w);
    *(ushort4*)(out + (size_t)i * 4) = *(const ushort4*)tmp;
}

// R[M x Nld] = A_virtual[M x Kd] * Wbig[Nld x Kd]^T + bias (Wbig row stride 768)
// BM=BN=128, BK=32, 256 threads = 4 waves in 2x2 grid, each wave 64x64 via
// 4x4 grid of 16x16x32 MFMA. Rows >= M read in-bounds garbage, stores guarded.
__global__ __launch_bounds__(256) void mfma_gemm(
    const __hip_bfloat16* __restrict__ embX,   // [.][256] stride 256
    const __hip_bfloat16* __restrict__ hprev,  // [.][512] stride 512 (k>=256)
    const __hip_bfloat16* __restrict__ Wbig,
    const float* __restrict__ biasbig,
    float* __restrict__ R,
    int M, int Nld, int Kd)
{
    __shared__ __hip_bfloat16 sA[128 * 32];
    __shared__ __hip_bfloat16 sB[128 * 32];
    const int t = threadIdx.x;
    const int bn0 = blockIdx.x * 128;
    const int bm0 = blockIdx.y * 128;
    const int lane = t & 63;
    const int wave = t >> 6;
    const int wr = wave >> 1, wc = wave & 1;
    const int lrow = lane & 15;
    const int q = lane >> 4;

    floatx4 acc[4][4];
    #pragma unroll
    for (int i = 0; i < 4; ++i)
        #pragma unroll
        for (int j = 0; j < 4; ++j) acc[i][j] = (floatx4){0.f, 0.f, 0.f, 0.f};

    const int ar0 = t >> 2;          // 0..63 (row within half-tile)
    const int acol = (t & 3) * 8;    // bf16 element col, 16B chunk

    for (int k0 = 0; k0 < Kd; k0 += 32) {
        const bool fromX = (k0 < 256);
        #pragma unroll
        for (int c = 0; c < 2; ++c) {
            int r = c * 64 + ar0;
            const __hip_bfloat16* g = fromX
                ? embX  + (size_t)(bm0 + r) * 256 + k0 + acol
                : hprev + (size_t)(bm0 + r) * 512 + (k0 - 256) + acol;
            load_lds16(g, &sA[c * 2048 + t * 8]);
        }
        #pragma unroll
        for (int c = 0; c < 2; ++c) {
            int r = c * 64 + ar0;
            load_lds16(Wbig + (size_t)(bn0 + r) * 768 + k0 + acol, &sB[c * 2048 + t * 8]);
        }
        __syncthreads();

        bf16x8 af[4], bfr[4];
        #pragma unroll
        for (int mi = 0; mi < 4; ++mi)
            af[mi] = *(const bf16x8*)&sA[(wr * 64 + mi * 16 + lrow) * 32 + q * 8];
        #pragma unroll
        for (int ni = 0; ni < 4; ++ni)
            bfr[ni] = *(const bf16x8*)&sB[(wc * 64 + ni * 16 + lrow) * 32 + q * 8];
        #pragma unroll
        for (int mi = 0; mi < 4; ++mi)
            #pragma unroll
            for (int ni = 0; ni < 4; ++ni)
                acc[mi][ni] = __builtin_amdgcn_mfma_f32_16x16x32_bf16(af[mi], bfr[ni], acc[mi][ni], 0, 0, 0);
        __syncthreads();
    }

    // C/D layout: col = lane&15, row = (lane>>4)*4 + reg
    #pragma unroll
    for (int mi = 0; mi < 4; ++mi) {
        int grow0 = bm0 + wr * 64 + mi * 16 + q * 4;
        #pragma unroll
        for (int ni = 0; ni < 4; ++ni) {
            int gcol = bn0 + wc * 64 + ni * 16 + lrow;
            float bv = biasbig[gcol];
            #pragma unroll
            for (int rr = 0; rr < 4; ++rr) {
                int grow = grow0 + rr;
                if (grow < M) R[(size_t)grow * Nld + gcol] = acc[mi][ni][rr] + bv;
            }
        }
    }
}

__global__ void pointwise_internal(const float* __restrict__ R,      // [n x 1280]
                                   const float* __restrict__ cprev,  // [2n x 256]
                                   __hip_bfloat16* __restrict__ hout,
                                   float* __restrict__ cout,
                                   int n)
{
    int idx = blockIdx.x * 256 + threadIdx.x;
    if (idx >= n * 256) return;
    int m = idx >> 8, d = idx & 255;
    const float* r = R + (size_t)m * 1280;
    float i  = sigf(r[d]);
    float o  = sigf(r[256 + d]);
    float u  = tanhf(r[512 + d]);
    float fl = sigf(r[768 + d]);
    float fr = sigf(r[1024 + d]);
    float cl = cprev[(size_t)m * 512 + d];
    float cr = cprev[(size_t)m * 512 + 256 + d];
    float c = i * u + fl * cl + fr * cr;
    cout[idx] = c;
    hout[idx] = __float2bfloat16(o * tanhf(c));
}

__global__ void pointwise_leaf(const float* __restrict__ R,   // [n x 768]
                               __hip_bfloat16* __restrict__ hout,
                               float* __restrict__ cout,
                               int n)
{
    int idx = blockIdx.x * 256 + threadIdx.x;
    if (idx >= n * 256) return;
    int m = idx >> 8, d = idx & 255;
    const float* r = R + (size_t)m * 768;
    float i = sigf(r[d]);
    float o = sigf(r[256 + d]);
    float u = tanhf(r[512 + d]);
    float c = i * u;
    cout[idx] = c;
    hout[idx] = __float2bfloat16(o * tanhf(c));
}

__global__ void write_out(const __hip_bfloat16* __restrict__ h, const float* __restrict__ c,
                          float* __restrict__ out)
{
    int t = threadIdx.x; // 256
    out[t] = __bfloat162float(h[t]);
    out[256 + t] = c[t];
}

extern "C" void kernel_launch(void* const* d_in, const int* in_sizes, int n_in,
                              void* d_out, int out_size, void* d_ws, size_t ws_size,
                              hipStream_t stream)
{
    const float* emb = (const float*)d_in[0];
    const float* Wi  = (const float*)d_in[1];
    const float* bi  = (const float*)d_in[2];
    const float* Ui  = (const float*)d_in[3];
    const float* Wo  = (const float*)d_in[4];
    const float* bo  = (const float*)d_in[5];
    const float* Uo  = (const float*)d_in[6];
    const float* Wu  = (const float*)d_in[7];
    const float* bu  = (const float*)d_in[8];
    const float* Uu  = (const float*)d_in[9];
    const float* Wf  = (const float*)d_in[10];
    const float* bf  = (const float*)d_in[11];
    const float* Uf  = (const float*)d_in[12];

    char* p = (char*)d_ws;
    __hip_bfloat16* Wbig = (__hip_bfloat16*)p;  p += (size_t)1280 * 768 * 2;
    float* biasbig       = (float*)p;           p += (size_t)1280 * 4;
    __hip_bfloat16* embB = (__hip_bfloat16*)p;  p += (size_t)65535 * 256 * 2;
    __hip_bfloat16* hbuf = (__hip_bfloat16*)p;  p += (size_t)65535 * 256 * 2;
    float* cbuf          = (float*)p;           p += (size_t)65535 * 256 * 4;
    float* Rbuf          = (float*)p;           // max(32768*768, 16384*1280)*4 = 96 MiB

    pack_weights<<<1280, 256, 0, stream>>>(Wi, bi, Ui, Wo, bo, Uo, Wu, bu, Uu, Wf, bf, Uf,
                                           Wbig, biasbig);
    convert_f32_bf16<<<(65535 * 256 / 4 + 255) / 256, 256, 0, stream>>>(emb, embB, 65535 * 256 / 4);

    // Leaves: level 15, n = 32768, start = 32767. Kd=256 (x only), Nld=768 (i,o,u).
    {
        const int n = 32768, start = n - 1;
        mfma_gemm<<<dim3(768 / 128, n / 128), 256, 0, stream>>>(
            embB + (size_t)start * 256, hbuf /*unused*/, Wbig, biasbig, Rbuf, n, 768, 256);
        pointwise_leaf<<<n, 256, 0, stream>>>(
            Rbuf, hbuf + (size_t)start * 256, cbuf + (size_t)start * 256, n);
    }

    // Internal levels, bottom-up.
    for (int l = 14; l >= 0; --l) {
        const int n = 1 << l;
        const int start = n - 1;
        const int startc = 2 * n - 1;
        mfma_gemm<<<dim3(1280 / 128, (n + 127) / 128), 256, 0, stream>>>(
            embB + (size_t)start * 256, hbuf + (size_t)startc * 256,
            Wbig, biasbig, Rbuf, n, 1280, 768);
        pointwise_internal<<<(n * 256 + 255) / 256, 256, 0, stream>>>(
            Rbuf, cbuf + (size_t)startc * 256,
            hbuf + (size_t)start * 256, cbuf + (size_t)start * 256, n);
    }

    write_out<<<1, 256, 0, stream>>>(hbuf, cbuf, (float*)d_out);
}